// Round 20
// baseline (503.595 us; speedup 1.0000x reference)
//
#include <hip/hip_runtime.h>

#define V 512
#define L 168
#define PLANE 86016          // 512*168
#define CHSTRIDE 2752512     // 32*512*168 elements per batch
#define B_ 16
#define HDRE 1052672         // header elems: M1,M2,M3,ANb (262144 each) + Wb 4096

typedef __attribute__((ext_vector_type(8))) short s16x8;
typedef __attribute__((ext_vector_type(4))) float f32x4;
typedef unsigned short u16;

__device__ inline short f2bf(float f) {
    unsigned u = __builtin_bit_cast(unsigned, f);
    u += 0x7FFF + ((u >> 16) & 1);
    return (short)(u >> 16);
}
__device__ inline float bf2f(u16 s) {
    return __builtin_bit_cast(float, ((unsigned)s) << 16);
}
__device__ inline void gll16(const u16* g, u16* lds) {
    __builtin_amdgcn_global_load_lds(
        (const __attribute__((address_space(1))) void*)g,
        (__attribute__((address_space(3))) void*)lds, 16, 0, 0);
}

// ---- prep2: M1[w][v]=bf16(anorm[v][w]); ANb[v][w] row-major; Wb = folded W' ---
__global__ __launch_bounds__(256) void prep2(const float* __restrict__ adj,
                                             const float* __restrict__ W,
                                             u16* __restrict__ M1,
                                             u16* __restrict__ ANb,
                                             u16* __restrict__ Wb) {
    if (blockIdx.x == V) {
        const float al = 0.05f, be = 0.95f;
        for (int i = threadIdx.x; i < 1024; i += 256) {
            const int o = i >> 5, c = i & 31;
            const float w0 = W[o * 128 + c];
            const float w1 = W[o * 128 + 32 + c];
            const float w2 = W[o * 128 + 64 + c];
            const float w3 = W[o * 128 + 96 + c];
            Wb[o * 128 + c]      = f2bf(w0 + al * (w1 + w2 + w3));
            Wb[o * 128 + 32 + c] = f2bf(be * (w1 + al * (w2 + w3)));
            Wb[o * 128 + 64 + c] = f2bf(be * be * (w2 + al * w3));
            Wb[o * 128 + 96 + c] = f2bf(be * be * be * w3);
        }
        return;
    }
    const int v = blockIdx.x;
    float s = 0.f;
    for (int w = threadIdx.x; w < V; w += 256)
        s += adj[v * V + w] + (w == v ? 1.f : 0.f);
    __shared__ float red[256];
    red[threadIdx.x] = s;
    __syncthreads();
    for (int off = 128; off > 0; off >>= 1) {
        if ((int)threadIdx.x < off) red[threadIdx.x] += red[threadIdx.x + off];
        __syncthreads();
    }
    const float inv = 1.f / red[0];
    for (int w = threadIdx.x; w < V; w += 256) {
        const short q = f2bf((adj[v * V + w] + (w == v ? 1.f : 0.f)) * inv);
        M1[w * V + v] = q;       // (anorm^T)[w][v]
        ANb[v * V + w] = q;      // anorm[v][w]
    }
}

// ---- powk: OUT[w][v] = bf16( sum_u X[w][u] * ANb[v][u] ) ----------------------
__global__ __launch_bounds__(256) void powk(const u16* __restrict__ X,
                                            const u16* __restrict__ ANb,
                                            u16* __restrict__ OUT) {
    const int w0 = (blockIdx.x >> 3) * 64, v0 = (blockIdx.x & 7) * 64;
    const int tid = threadIdx.x, lane = tid & 63, wave = tid >> 6;
    const int colb = lane & 15, kg = lane >> 4;
    f32x4 acc[4];
#pragma unroll
    for (int i = 0; i < 4; i++) acc[i] = (f32x4){0.f, 0.f, 0.f, 0.f};
#pragma unroll 4
    for (int kk = 0; kk < 16; kk++) {
        const int u = kk * 32 + kg * 8;
        const s16x8 bfr = *(const s16x8*)&ANb[(size_t)(v0 + wave * 16 + colb) * 512 + u];
#pragma unroll
        for (int mt = 0; mt < 4; mt++) {
            const s16x8 afr = *(const s16x8*)&X[(size_t)(w0 + mt * 16 + colb) * 512 + u];
            acc[mt] = __builtin_amdgcn_mfma_f32_16x16x32_bf16(afr, bfr, acc[mt], 0, 0, 0);
        }
    }
#pragma unroll
    for (int mt = 0; mt < 4; mt++)
#pragma unroll
        for (int r = 0; r < 4; r++)
            OUT[(size_t)(w0 + mt * 16 + kg * 4 + r) * 512 + v0 + wave * 16 + colb] =
                (u16)f2bf(acc[mt][r]);
}

// ---- cvtT: xa[b][n=(l*32+c)][v] = bf16(x[b][c][v][l]) — L-MAJOR n -------------
__global__ __launch_bounds__(256) void cvtT(const float* __restrict__ x,
                                            u16* __restrict__ xa) {
    const int b = blockIdx.z >> 5, c = blockIdx.z & 31;
    const int v0 = blockIdx.y * 64, l0 = blockIdx.x * 64;
    const int tid = threadIdx.x;
    __shared__ float T[64][65];
    const float* xp = x + (size_t)b * CHSTRIDE + (size_t)c * PLANE;
    u16* xo = xa + (size_t)b * CHSTRIDE;
#pragma unroll
    for (int rep = 0; rep < 16; rep++) {
        const int idx = rep * 256 + tid;
        const int vv = idx >> 6, ll = idx & 63;
        if (l0 + ll < L) T[vv][ll] = xp[(size_t)(v0 + vv) * L + l0 + ll];
    }
    __syncthreads();
#pragma unroll
    for (int rep = 0; rep < 16; rep++) {
        const int idx = rep * 256 + tid;
        const int ll = idx >> 6, vv = idx & 63;
        if (l0 + ll < L)
            xo[(size_t)((l0 + ll) * 32 + c) * 512 + v0 + vv] = f2bf(T[vv][ll]);
    }
}

// ---- propOut: FUSED props + outconv — r16 core, CONTINUOUS 24-step pipeline ---
// Per block (n-tile 128 l-major = 4l x 32c, w-tile 128): one unrolled loop over
// (k,t): BK=64 dbuf staging (r16-certified), 3 live acc sets, cross-pass
// prefetch never drains. Epilogue once: bounce_k -> CsT -> OUTACC_k sequenced.
__global__ __launch_bounds__(256, 2) void propOut(const u16* __restrict__ xa,
                                                  const u16* __restrict__ AS,
                                                  const u16* __restrict__ Wb,
                                                  const float* __restrict__ bias,
                                                  u16* __restrict__ tmpb) {
    const int b = blockIdx.z;
    const int logical = (blockIdx.x & 7) * 21 + (blockIdx.x >> 3);  // 168 = 8*21
    const int ntile = logical >> 2, wq = logical & 3;
    const int n0 = ntile * 128, w0 = wq * 128, l0 = ntile * 4;
    const int tid = threadIdx.x, lane = tid & 63, wave = tid >> 6;
    const int wm = wave >> 1, wn = wave & 1;
    const int colb = lane & 15, kg = lane >> 4;
    __shared__ __align__(16) u16 SH[2][16384];     // dbuf staging, 64 KB total
    u16* flat = &SH[0][0];                         // CsT overlay (34816 B)
    const size_t sB = (size_t)b * CHSTRIDE;
    const u16* srcb = xa + sB;

    f32x4 acc1[4][4], acc2[4][4], acc3[4][4];
#pragma unroll
    for (int i = 0; i < 4; i++)
#pragma unroll
        for (int j = 0; j < 4; j++) {
            acc1[i][j] = (f32x4){0.f, 0.f, 0.f, 0.f};
            acc2[i][j] = acc1[i][j];
            acc3[i][j] = acc1[i][j];
        }

    // stage global step T (T = kt*8 + tt): A_kt v-slab tt + B v-slab tt
#define STAGE(T, BUF)                                                             \
    {                                                                             \
        const u16* Ak = AS + (size_t)((T) >> 3) * 262144;                         \
        const int v0s = ((T) & 7) * 64;                                           \
        _Pragma("unroll") for (int i = 0; i < 4; i++) {                           \
            const int cc = wave * 4 + i, oct = cc >> 1, half = cc & 1;            \
            const int row = half * 64 + lane;                                     \
            gll16(&Ak[(size_t)(w0 + row) * 512 + v0s + oct * 8],                  \
                  &SH[BUF][oct * 1024 + half * 512]);                             \
            gll16(&srcb[(size_t)(n0 + row) * 512 + v0s + oct * 8],                \
                  &SH[BUF][8192 + oct * 1024 + half * 512]);                      \
        }                                                                         \
    }

#define MFMASTEP(BUF, ACC)                                                        \
    _Pragma("unroll") for (int kk = 0; kk < 2; kk++) {                            \
        const int cq = kk * 4 + kg;                                               \
        s16x8 afr[4], bfr[4];                                                     \
        _Pragma("unroll") for (int mt = 0; mt < 4; mt++)                          \
            afr[mt] = *(const s16x8*)&SH[BUF][cq * 1024 +                         \
                                             (wm * 64 + mt * 16 + colb) * 8];     \
        _Pragma("unroll") for (int nt = 0; nt < 4; nt++)                          \
            bfr[nt] = *(const s16x8*)&SH[BUF][8192 + cq * 1024 +                  \
                                             (wn * 64 + nt * 16 + colb) * 8];     \
        _Pragma("unroll") for (int mt = 0; mt < 4; mt++)                          \
            _Pragma("unroll") for (int nt = 0; nt < 4; nt++)                      \
                ACC[mt][nt] = __builtin_amdgcn_mfma_f32_16x16x32_bf16(            \
                    afr[mt], bfr[nt], ACC[mt][nt], 0, 0, 0);                      \
    }

    STAGE(0, 0);
    __syncthreads();
#pragma unroll
    for (int t = 0; t < 24; t++) {
        const int buf = t & 1;
        if (t < 23) STAGE(t + 1, buf ^ 1);   // continuous cross-pass prefetch
        __builtin_amdgcn_s_setprio(1);
        if (t < 8) {
            MFMASTEP(buf, acc1);
        } else if (t < 16) {
            MFMASTEP(buf, acc2);
        } else {
            MFMASTEP(buf, acc3);
        }
        __builtin_amdgcn_s_setprio(0);
        __syncthreads();   // drains stage(t+1); hazard arg identical to r16
    }
#undef MFMASTEP
#undef STAGE

    // ---- epilogue (r16-certified chain): per k { bounce -> CsT; OUTACC_k } ---
#define BOUNCE(ACC)                                                               \
    _Pragma("unroll") for (int mt = 0; mt < 4; mt++) {                            \
        const int wr = wm * 64 + mt * 16 + kg * 4;                                \
        _Pragma("unroll") for (int nt = 0; nt < 4; nt++) {                        \
            const int nn = wn * 64 + nt * 16 + colb;                              \
            _Pragma("unroll") for (int r = 0; r < 4; r++)                         \
                flat[(wr + r) * 136 + nn] = (u16)f2bf(ACC[mt][nt][r]);            \
        }                                                                         \
    }

#define OUTACC(KP)                                                                \
    _Pragma("unroll") for (int pf = 0; pf < 8; pf++) {                            \
        const s16x8 bfr = *(const s16x8*)&flat[(pf * 16 + colb) * 136 +           \
                                               wave * 32 + kg * 8];               \
        _Pragma("unroll") for (int mt = 0; mt < 2; mt++) {                        \
            const s16x8 afr = *(const s16x8*)&Wb[(mt * 16 + colb) * 128 +         \
                                                 (KP) * 32 + kg * 8];             \
            aco[mt][pf] = __builtin_amdgcn_mfma_f32_16x16x32_bf16(                \
                afr, bfr, aco[mt][pf], 0, 0, 0);                                  \
        }                                                                         \
    }

    BOUNCE(acc1);
    __syncthreads();

    f32x4 aco[2][8];
#pragma unroll
    for (int i = 0; i < 2; i++)
#pragma unroll
        for (int j = 0; j < 8; j++) aco[i][j] = (f32x4){0.f, 0.f, 0.f, 0.f};

    // OUTACC0: p0 = xa slice, direct global reads (r16-certified pattern)
#pragma unroll
    for (int pf = 0; pf < 8; pf++) {
        s16x8 bfr;
#pragma unroll
        for (int j = 0; j < 8; j++)
            bfr[j] = (short)srcb[(size_t)(n0 + wave * 32 + kg * 8 + j) * 512 +
                                 w0 + pf * 16 + colb];
#pragma unroll
        for (int mt = 0; mt < 2; mt++) {
            const s16x8 afr = *(const s16x8*)&Wb[(mt * 16 + colb) * 128 + kg * 8];
            aco[mt][pf] = __builtin_amdgcn_mfma_f32_16x16x32_bf16(afr, bfr, aco[mt][pf], 0, 0, 0);
        }
    }
    OUTACC(1);
    __syncthreads();
    BOUNCE(acc2);
    __syncthreads();
    OUTACC(2);
    __syncthreads();
    BOUNCE(acc3);
    __syncthreads();
    OUTACC(3);
#undef BOUNCE
#undef OUTACC

    // ---- store: tmpb[o][l][v=w] = bf16(bias + aco) ---------------------------
#pragma unroll
    for (int mt = 0; mt < 2; mt++)
#pragma unroll
        for (int pf = 0; pf < 8; pf++)
#pragma unroll
            for (int r = 0; r < 4; r++) {
                const int o = mt * 16 + kg * 4 + r;
                tmpb[sB + (size_t)o * PLANE + (size_t)(l0 + wave) * 512 +
                     w0 + pf * 16 + colb] = (u16)f2bf(bias[o] + aco[mt][pf][r]);
            }
}

// ---- transT_b: out[b][o][v][l] = f32(tmpb[b][o][l][v]) ------------------------
__global__ __launch_bounds__(256) void transT_b(const u16* __restrict__ tmpb,
                                                float* __restrict__ out) {
    const int o = blockIdx.y, b = blockIdx.z;
    const int vt = blockIdx.x / 3, lt = blockIdx.x % 3;
    const int v0 = vt * 64, l0 = lt * 64;
    const int tid = threadIdx.x;
    __shared__ float T[64][65];
    const u16* tp = tmpb + (size_t)b * CHSTRIDE + (size_t)o * PLANE;
    float* op = out + (size_t)b * CHSTRIDE + (size_t)o * PLANE;
#pragma unroll
    for (int rep = 0; rep < 16; rep++) {
        const int idx = rep * 256 + tid;
        const int ll = idx >> 6, vv = idx & 63;    // read: v-contiguous lanes
        if (l0 + ll < L) T[ll][vv] = bf2f(tp[(size_t)(l0 + ll) * 512 + v0 + vv]);
    }
    __syncthreads();
#pragma unroll
    for (int rep = 0; rep < 16; rep++) {
        const int idx = rep * 256 + tid;
        const int vv = idx >> 6, ll = idx & 63;    // write: l-contiguous lanes
        if (l0 + ll < L) op[(size_t)(v0 + vv) * L + l0 + ll] = T[ll][vv];
    }
}

extern "C" void kernel_launch(void* const* d_in, const int* in_sizes, int n_in,
                              void* d_out, int out_size, void* d_ws, size_t ws_size,
                              hipStream_t stream) {
    const float* x = (const float*)d_in[0];
    const float* adj = (const float*)d_in[1];
    const float* W = (const float*)d_in[2];
    const float* bias = (const float*)d_in[3];
    float* out = (float*)d_out;

    // Single-chunk path: header in the TAIL of d_out (dead until the final
    // transT_b, which runs after every propOut consumed it). If ws can't hold
    // all 16 batches (chunked path), header must live in ws instead — d_out's
    // tail gets overwritten by chunk 0's transT before later propOuts read it.
    const bool single = ws_size >= (size_t)4 * CHSTRIDE * B_;
    u16* hdr;
    u16* hbuf;
    int nbc;
    if (single) {
        hdr = (u16*)((char*)d_out + (size_t)out_size * 4 - (size_t)HDRE * 2 - 256);
        hbuf = (u16*)d_ws;
        nbc = B_;
    } else {
        hdr = (u16*)d_ws;
        hbuf = (u16*)((char*)d_ws + (size_t)HDRE * 2 + 256);
        const size_t avail = ws_size - (size_t)HDRE * 2 - 256;
        nbc = (int)(avail / ((size_t)4 * CHSTRIDE));
        if (nbc < 1) nbc = 1;                 // requires ws >= ~13 MB
        if (nbc > B_) nbc = B_;
    }
    u16* AS = hdr;                            // [M1;M2;M3]
    u16* M1 = AS;
    u16* M2 = AS + 262144;
    u16* M3 = AS + 2 * 262144;
    u16* ANb = AS + 3 * 262144;
    u16* Wb = AS + 4 * 262144;

    prep2<<<V + 1, 256, 0, stream>>>(adj, W, M1, ANb, Wb);
    powk<<<64, 256, 0, stream>>>(M1, ANb, M2);
    powk<<<64, 256, 0, stream>>>(M2, ANb, M3);

    for (int b0 = 0; b0 < B_; b0 += nbc) {
        const int nb = (B_ - b0 < nbc) ? (B_ - b0) : nbc;
        const float* xb = x + (size_t)b0 * CHSTRIDE;
        float* outb = out + (size_t)b0 * CHSTRIDE;
        u16* xa = hbuf;
        u16* tmpb = hbuf + (size_t)nbc * CHSTRIDE;

        cvtT<<<dim3(3, 8, nb * 32), 256, 0, stream>>>(xb, xa);
        propOut<<<dim3(168, 1, nb), 256, 0, stream>>>(xa, AS, Wb, bias, tmpb);
        transT_b<<<dim3(24, 32, nb), 256, 0, stream>>>(tmpb, outb);
    }
}

// Round 21
// 459.280 us; speedup vs baseline: 1.0965x; 1.0965x over previous
//
#include <hip/hip_runtime.h>

#define V 512
#define L 168
#define PLANE 86016          // 512*168
#define CHSTRIDE 2752512     // 32*512*168 elements per batch
#define B_ 16
#define HDRE 1052672         // header elems: M1,M2,M3,ANb (262144 each) + Wb 4096

typedef __attribute__((ext_vector_type(8))) short s16x8;
typedef __attribute__((ext_vector_type(4))) float f32x4;
typedef unsigned short u16;

__device__ inline short f2bf(float f) {
    unsigned u = __builtin_bit_cast(unsigned, f);
    u += 0x7FFF + ((u >> 16) & 1);
    return (short)(u >> 16);
}
__device__ inline float bf2f(u16 s) {
    return __builtin_bit_cast(float, ((unsigned)s) << 16);
}
__device__ inline void gll16(const u16* g, u16* lds) {
    __builtin_amdgcn_global_load_lds(
        (const __attribute__((address_space(1))) void*)g,
        (__attribute__((address_space(3))) void*)lds, 16, 0, 0);
}

// ---- prep2: M1[w][v]=bf16(anorm[v][w]); ANb[v][w] row-major; Wb = folded W' ---
// out = b + W0'x + W1'p1 + W2'p2 + W3'p3, pk = anorm^k prop (algebraic fold)
__global__ __launch_bounds__(256) void prep2(const float* __restrict__ adj,
                                             const float* __restrict__ W,
                                             u16* __restrict__ M1,
                                             u16* __restrict__ ANb,
                                             u16* __restrict__ Wb) {
    if (blockIdx.x == V) {
        const float al = 0.05f, be = 0.95f;
        for (int i = threadIdx.x; i < 1024; i += 256) {
            const int o = i >> 5, c = i & 31;
            const float w0 = W[o * 128 + c];
            const float w1 = W[o * 128 + 32 + c];
            const float w2 = W[o * 128 + 64 + c];
            const float w3 = W[o * 128 + 96 + c];
            Wb[o * 128 + c]      = f2bf(w0 + al * (w1 + w2 + w3));
            Wb[o * 128 + 32 + c] = f2bf(be * (w1 + al * (w2 + w3)));
            Wb[o * 128 + 64 + c] = f2bf(be * be * (w2 + al * w3));
            Wb[o * 128 + 96 + c] = f2bf(be * be * be * w3);
        }
        return;
    }
    const int v = blockIdx.x;
    float s = 0.f;
    for (int w = threadIdx.x; w < V; w += 256)
        s += adj[v * V + w] + (w == v ? 1.f : 0.f);
    __shared__ float red[256];
    red[threadIdx.x] = s;
    __syncthreads();
    for (int off = 128; off > 0; off >>= 1) {
        if ((int)threadIdx.x < off) red[threadIdx.x] += red[threadIdx.x + off];
        __syncthreads();
    }
    const float inv = 1.f / red[0];
    for (int w = threadIdx.x; w < V; w += 256) {
        const short q = f2bf((adj[v * V + w] + (w == v ? 1.f : 0.f)) * inv);
        M1[w * V + v] = q;       // (anorm^T)[w][v]
        ANb[v * V + w] = q;      // anorm[v][w]
    }
}

// ---- powk: OUT[w][v] = bf16( sum_u X[w][u] * ANb[v][u] ) ----------------------
__global__ __launch_bounds__(256) void powk(const u16* __restrict__ X,
                                            const u16* __restrict__ ANb,
                                            u16* __restrict__ OUT) {
    const int w0 = (blockIdx.x >> 3) * 64, v0 = (blockIdx.x & 7) * 64;
    const int tid = threadIdx.x, lane = tid & 63, wave = tid >> 6;
    const int colb = lane & 15, kg = lane >> 4;
    f32x4 acc[4];
#pragma unroll
    for (int i = 0; i < 4; i++) acc[i] = (f32x4){0.f, 0.f, 0.f, 0.f};
#pragma unroll 4
    for (int kk = 0; kk < 16; kk++) {
        const int u = kk * 32 + kg * 8;
        const s16x8 bfr = *(const s16x8*)&ANb[(size_t)(v0 + wave * 16 + colb) * 512 + u];
#pragma unroll
        for (int mt = 0; mt < 4; mt++) {
            const s16x8 afr = *(const s16x8*)&X[(size_t)(w0 + mt * 16 + colb) * 512 + u];
            acc[mt] = __builtin_amdgcn_mfma_f32_16x16x32_bf16(afr, bfr, acc[mt], 0, 0, 0);
        }
    }
#pragma unroll
    for (int mt = 0; mt < 4; mt++)
#pragma unroll
        for (int r = 0; r < 4; r++)
            OUT[(size_t)(w0 + mt * 16 + kg * 4 + r) * 512 + v0 + wave * 16 + colb] =
                (u16)f2bf(acc[mt][r]);
}

// ---- cvtT: xa[b][n=(l*32+c)][v] = bf16(x[b][c][v][l]) — L-MAJOR n -------------
__global__ __launch_bounds__(256) void cvtT(const float* __restrict__ x,
                                            u16* __restrict__ xa) {
    const int b = blockIdx.z >> 5, c = blockIdx.z & 31;
    const int v0 = blockIdx.y * 64, l0 = blockIdx.x * 64;
    const int tid = threadIdx.x;
    __shared__ float T[64][65];
    const float* xp = x + (size_t)b * CHSTRIDE + (size_t)c * PLANE;
    u16* xo = xa + (size_t)b * CHSTRIDE;
#pragma unroll
    for (int rep = 0; rep < 16; rep++) {
        const int idx = rep * 256 + tid;
        const int vv = idx >> 6, ll = idx & 63;
        if (l0 + ll < L) T[vv][ll] = xp[(size_t)(v0 + vv) * L + l0 + ll];
    }
    __syncthreads();
#pragma unroll
    for (int rep = 0; rep < 16; rep++) {
        const int idx = rep * 256 + tid;
        const int ll = idx >> 6, vv = idx & 63;
        if (l0 + ll < L)
            xo[(size_t)((l0 + ll) * 32 + c) * 512 + v0 + vv] = f2bf(T[vv][ll]);
    }
}

// ---- propOut: FUSED props + outconv (r16-certified best: 462 us config) -------
// Per block (n-tile 128 l-major = 4l x 32c, w-tile 128): for k=1..3
// { dbuf GEMM p_k = M_k @ xa (16x16x32); bounce acc->CsT[w][n];
//   aco += Wk' x p_k (c-contraction) }.  OUTACC0 from global xa.
// p's never touch HBM; writes only bf16 tmpb[o][l][v] (+bias).
__global__ __launch_bounds__(256, 2) void propOut(const u16* __restrict__ xa,
                                                  const u16* __restrict__ AS,
                                                  const u16* __restrict__ Wb,
                                                  const float* __restrict__ bias,
                                                  u16* __restrict__ tmpb) {
    const int b = blockIdx.z;
    const int logical = (blockIdx.x & 7) * 21 + (blockIdx.x >> 3);  // 168 = 8*21
    const int ntile = logical >> 2, wq = logical & 3;
    const int n0 = ntile * 128, w0 = wq * 128, l0 = ntile * 4;
    const int tid = threadIdx.x, lane = tid & 63, wave = tid >> 6;
    const int wm = wave >> 1, wn = wave & 1;
    const int colb = lane & 15, kg = lane >> 4;
    __shared__ __align__(16) u16 SH[2][16384];     // dbuf staging, 64 KB total
    u16* flat = &SH[0][0];                         // CsT overlay (34816 B)
    const size_t sB = (size_t)b * CHSTRIDE;
    const u16* srcb = xa + sB;

    f32x4 aco[2][8];                               // out acc: o-tiles x pos-frags
#pragma unroll
    for (int i = 0; i < 2; i++)
#pragma unroll
        for (int j = 0; j < 8; j++) aco[i][j] = (f32x4){0.f, 0.f, 0.f, 0.f};

    // ---- OUTACC0: aco += W0' x p0, p0 = xa slice -----------------------------
#pragma unroll
    for (int pf = 0; pf < 8; pf++) {
        s16x8 bfr;
#pragma unroll
        for (int j = 0; j < 8; j++)
            bfr[j] = (short)srcb[(size_t)(n0 + wave * 32 + kg * 8 + j) * 512 +
                                 w0 + pf * 16 + colb];
#pragma unroll
        for (int mt = 0; mt < 2; mt++) {
            const s16x8 afr = *(const s16x8*)&Wb[(mt * 16 + colb) * 128 + kg * 8];
            aco[mt][pf] = __builtin_amdgcn_mfma_f32_16x16x32_bf16(afr, bfr, aco[mt][pf], 0, 0, 0);
        }
    }

#define STAGE(T, BUF, AK)                                                         \
    {                                                                             \
        const int v0s = (T) * 64;                                                 \
        _Pragma("unroll") for (int i = 0; i < 4; i++) {                           \
            const int cc = wave * 4 + i, oct = cc >> 1, half = cc & 1;            \
            const int row = half * 64 + lane;                                     \
            gll16(&AK[(size_t)(w0 + row) * 512 + v0s + oct * 8],                  \
                  &SH[BUF][oct * 1024 + half * 512]);                             \
            gll16(&srcb[(size_t)(n0 + row) * 512 + v0s + oct * 8],                \
                  &SH[BUF][8192 + oct * 1024 + half * 512]);                      \
        }                                                                         \
    }

#define MFMASTEP(BUF)                                                             \
    _Pragma("unroll") for (int kk = 0; kk < 2; kk++) {                            \
        const int cq = kk * 4 + kg;                                               \
        s16x8 afr[4], bfr[4];                                                     \
        _Pragma("unroll") for (int mt = 0; mt < 4; mt++)                          \
            afr[mt] = *(const s16x8*)&SH[BUF][cq * 1024 +                         \
                                             (wm * 64 + mt * 16 + colb) * 8];     \
        _Pragma("unroll") for (int nt = 0; nt < 4; nt++)                          \
            bfr[nt] = *(const s16x8*)&SH[BUF][8192 + cq * 1024 +                  \
                                             (wn * 64 + nt * 16 + colb) * 8];     \
        _Pragma("unroll") for (int mt = 0; mt < 4; mt++)                          \
            _Pragma("unroll") for (int nt = 0; nt < 4; nt++)                      \
                acc[mt][nt] = __builtin_amdgcn_mfma_f32_16x16x32_bf16(            \
                    afr[mt], bfr[nt], acc[mt][nt], 0, 0, 0);                      \
    }

#define PASS(KP)                                                                  \
    {                                                                             \
        const u16* Ak = AS + (size_t)((KP) - 1) * 262144;                         \
        f32x4 acc[4][4];                                                          \
        _Pragma("unroll") for (int i = 0; i < 4; i++)                             \
            _Pragma("unroll") for (int j = 0; j < 4; j++)                         \
                acc[i][j] = (f32x4){0.f, 0.f, 0.f, 0.f};                          \
        STAGE(0, 0, Ak);                                                          \
        __syncthreads();                                                          \
        _Pragma("unroll") for (int t = 0; t < 8; t++) {                           \
            const int buf = t & 1;                                                \
            if (t < 7) STAGE(t + 1, buf ^ 1, Ak);                                 \
            __builtin_amdgcn_s_setprio(1);                                        \
            MFMASTEP(buf);                                                        \
            __builtin_amdgcn_s_setprio(0);                                        \
            __syncthreads();                                                      \
        }                                                                         \
        /* bounce acc -> CsT[w_local][n_local], pitch 136 */                      \
        _Pragma("unroll") for (int mt = 0; mt < 4; mt++) {                        \
            const int wr = wm * 64 + mt * 16 + kg * 4;                            \
            _Pragma("unroll") for (int nt = 0; nt < 4; nt++) {                    \
                const int nn = wn * 64 + nt * 16 + colb;                          \
                _Pragma("unroll") for (int r = 0; r < 4; r++)                     \
                    flat[(wr + r) * 136 + nn] = (u16)f2bf(acc[mt][nt][r]);        \
            }                                                                     \
        }                                                                         \
        __syncthreads();                                                          \
        /* OUTACC: aco += Wk' x p_k (contraction over c) */                       \
        _Pragma("unroll") for (int pf = 0; pf < 8; pf++) {                        \
            const s16x8 bfr = *(const s16x8*)&flat[(pf * 16 + colb) * 136 +       \
                                                   wave * 32 + kg * 8];           \
            _Pragma("unroll") for (int mt = 0; mt < 2; mt++) {                    \
                const s16x8 afr = *(const s16x8*)&Wb[(mt * 16 + colb) * 128 +     \
                                                     (KP) * 32 + kg * 8];         \
                aco[mt][pf] = __builtin_amdgcn_mfma_f32_16x16x32_bf16(            \
                    afr, bfr, aco[mt][pf], 0, 0, 0);                              \
            }                                                                     \
        }                                                                         \
        __syncthreads();                                                          \
    }

    PASS(1)
    PASS(2)
    PASS(3)
#undef PASS
#undef MFMASTEP
#undef STAGE

    // ---- epilogue: tmpb[o][l][v=w] = bf16(bias + aco) ------------------------
#pragma unroll
    for (int mt = 0; mt < 2; mt++)
#pragma unroll
        for (int pf = 0; pf < 8; pf++)
#pragma unroll
            for (int r = 0; r < 4; r++) {
                const int o = mt * 16 + kg * 4 + r;
                tmpb[sB + (size_t)o * PLANE + (size_t)(l0 + wave) * 512 +
                     w0 + pf * 16 + colb] = (u16)f2bf(bias[o] + aco[mt][pf][r]);
            }
}

// ---- transT_b: out[b][o][v][l] = f32(tmpb[b][o][l][v]) ------------------------
__global__ __launch_bounds__(256) void transT_b(const u16* __restrict__ tmpb,
                                                float* __restrict__ out) {
    const int o = blockIdx.y, b = blockIdx.z;
    const int vt = blockIdx.x / 3, lt = blockIdx.x % 3;
    const int v0 = vt * 64, l0 = lt * 64;
    const int tid = threadIdx.x;
    __shared__ float T[64][65];
    const u16* tp = tmpb + (size_t)b * CHSTRIDE + (size_t)o * PLANE;
    float* op = out + (size_t)b * CHSTRIDE + (size_t)o * PLANE;
#pragma unroll
    for (int rep = 0; rep < 16; rep++) {
        const int idx = rep * 256 + tid;
        const int ll = idx >> 6, vv = idx & 63;    // read: v-contiguous lanes
        if (l0 + ll < L) T[ll][vv] = bf2f(tp[(size_t)(l0 + ll) * 512 + v0 + vv]);
    }
    __syncthreads();
#pragma unroll
    for (int rep = 0; rep < 16; rep++) {
        const int idx = rep * 256 + tid;
        const int vv = idx >> 6, ll = idx & 63;    // write: l-contiguous lanes
        if (l0 + ll < L) op[(size_t)(v0 + vv) * L + l0 + ll] = T[ll][vv];
    }
}

extern "C" void kernel_launch(void* const* d_in, const int* in_sizes, int n_in,
                              void* d_out, int out_size, void* d_ws, size_t ws_size,
                              hipStream_t stream) {
    const float* x = (const float*)d_in[0];
    const float* adj = (const float*)d_in[1];
    const float* W = (const float*)d_in[2];
    const float* bias = (const float*)d_in[3];
    float* out = (float*)d_out;

    // Single-chunk path: header in the TAIL of d_out (dead until the final
    // transT_b, which runs after every propOut consumed it). Chunked path:
    // header must live in ws — d_out's tail would be overwritten by chunk 0's
    // transT before later propOuts read it.
    const bool single = ws_size >= (size_t)4 * CHSTRIDE * B_;
    u16* hdr;
    u16* hbuf;
    int nbc;
    if (single) {
        hdr = (u16*)((char*)d_out + (size_t)out_size * 4 - (size_t)HDRE * 2 - 256);
        hbuf = (u16*)d_ws;
        nbc = B_;
    } else {
        hdr = (u16*)d_ws;
        hbuf = (u16*)((char*)d_ws + (size_t)HDRE * 2 + 256);
        const size_t avail = ws_size - (size_t)HDRE * 2 - 256;
        nbc = (int)(avail / ((size_t)4 * CHSTRIDE));
        if (nbc < 1) nbc = 1;                 // requires ws >= ~13 MB
        if (nbc > B_) nbc = B_;
    }
    u16* AS = hdr;                            // [M1;M2;M3]
    u16* M1 = AS;
    u16* M2 = AS + 262144;
    u16* M3 = AS + 2 * 262144;
    u16* ANb = AS + 3 * 262144;
    u16* Wb = AS + 4 * 262144;

    prep2<<<V + 1, 256, 0, stream>>>(adj, W, M1, ANb, Wb);
    powk<<<64, 256, 0, stream>>>(M1, ANb, M2);
    powk<<<64, 256, 0, stream>>>(M2, ANb, M3);

    for (int b0 = 0; b0 < B_; b0 += nbc) {
        const int nb = (B_ - b0 < nbc) ? (B_ - b0) : nbc;
        const float* xb = x + (size_t)b0 * CHSTRIDE;
        float* outb = out + (size_t)b0 * CHSTRIDE;
        u16* xa = hbuf;
        u16* tmpb = hbuf + (size_t)nbc * CHSTRIDE;

        cvtT<<<dim3(3, 8, nb * 32), 256, 0, stream>>>(xb, xa);
        propOut<<<dim3(168, 1, nb), 256, 0, stream>>>(xa, AS, Wb, bias, tmpb);
        transT_b<<<dim3(24, 32, nb), 256, 0, stream>>>(tmpb, outb);
    }
}